// Round 2
// baseline (939.082 us; speedup 1.0000x reference)
//
#include <hip/hip_runtime.h>
#include <hip/hip_bf16.h>
#include <cstdint>
#include <cstddef>

// Problem constants
#define B_TOK 8192
#define HID   4096
#define NH    32
#define NKV   8
#define DH    128
#define RB    128
#define KDIM  4096
#define NOUT  5120   // q (32*128) + k (8*128) columns; v columns are never used
#define QKVW  6144

typedef __bf16 bf16x8 __attribute__((ext_vector_type(8)));
typedef __bf16 bf16x4 __attribute__((ext_vector_type(4)));
typedef float  f32x4  __attribute__((ext_vector_type(4)));

// ---- async global->LDS, 16B per lane. LDS dest = wave-uniform base + lane*16 ----
__device__ __forceinline__ void async_ld16(const void* g, void* l) {
  __builtin_amdgcn_global_load_lds(
      (__attribute__((address_space(1))) void*)(g),
      (__attribute__((address_space(3))) void*)(l), 16, 0, 0);
}

// (tanh(x)+1)/2 == sigmoid(2x) = 1/(1+exp2(-2*log2e*x))
__device__ __forceinline__ float code_of(float x) {
  const float e = exp2f(x * -2.885390081777927f);
  return __builtin_amdgcn_rcpf(1.0f + e);
}

// ---------------- conversion kernels ----------------

__global__ void conv_hidden_kernel(const float* __restrict__ x,
                                   __bf16* __restrict__ y, int n8) {
  const int i = blockIdx.x * 256 + threadIdx.x;
  if (i >= n8) return;
  const float4 v0 = ((const float4*)x)[2 * i];
  const float4 v1 = ((const float4*)x)[2 * i + 1];
  bf16x8 o;
  o[0] = (__bf16)v0.x; o[1] = (__bf16)v0.y; o[2] = (__bf16)v0.z; o[3] = (__bf16)v0.w;
  o[4] = (__bf16)v1.x; o[5] = (__bf16)v1.y; o[6] = (__bf16)v1.z; o[7] = (__bf16)v1.w;
  ((bf16x8*)y)[i] = o;
}

// proj_w [4096][6144] -> Wt [5120][4096] bf16 (transpose of first 5120 cols)
__global__ void conv_wt_kernel(const float* __restrict__ W, __bf16* __restrict__ Wt) {
  __shared__ float t[32][33];
  const int n0 = blockIdx.x * 32;   // over NOUT
  const int k0 = blockIdx.y * 32;   // over KDIM
  const int tx = threadIdx.x;       // 0..31
  const int ty = threadIdx.y;       // 0..7
#pragma unroll
  for (int j = 0; j < 4; ++j)
    t[ty + j * 8][tx] = W[(size_t)(k0 + ty + j * 8) * QKVW + n0 + tx];
  __syncthreads();
#pragma unroll
  for (int j = 0; j < 4; ++j)
    Wt[(size_t)(n0 + ty + j * 8) * KDIM + k0 + tx] = (__bf16)t[tx][ty + j * 8];
}

// hash_w [128][128] -> hwT [rbit][d] bf16
__global__ void conv_hash_kernel(const float* __restrict__ hw, __bf16* __restrict__ hwT) {
  const int r = blockIdx.x;    // rbit
  const int d = threadIdx.x;   // dim
  hwT[r * RB + d] = (__bf16)hw[(size_t)d * RB + r];
}

// ---------------- main GEMM: C[8192][5120] = A[8192][4096] @ Bt[5120][4096]^T + bias ----------------
// LDS staging is in MFMA-FRAGMENT ORDER: each 16-row x 32-col chunk stores the
// data for lane L at chunk_base + L*16B with L = (kc<<4)|row, matching both the
// global_load_lds DMA write pattern (base + lane*16) AND the fragment read
// pattern (addr = chunk_base + lane*16 -> linear in lane -> zero bank conflict).

__global__ void gemm_qk(const __bf16* __restrict__ A,
                        const __bf16* __restrict__ Bt,
                        const float* __restrict__ bias,
                        __bf16* __restrict__ C) {
  __shared__ __bf16 As[128 * 32];
  __shared__ __bf16 Bs[128 * 32];

  const int tid  = threadIdx.x;
  const int lane = tid & 63;
  const int wave = tid >> 6;
  const int m0 = blockIdx.y * 128;
  const int n0 = blockIdx.x * 128;

  // staging: lane L fetches (row = L&15, k-chunk = L>>4) of the wave's chunk
  const int r0  = lane & 15;
  const int kc8 = (lane >> 4) * 8;

  const __bf16* ga0 = A + (size_t)(m0 + wave * 16 + r0) * KDIM + kc8;
  const __bf16* ga1 = ga0 + (size_t)64 * KDIM;
  const __bf16* gb0 = Bt + (size_t)(n0 + wave * 16 + r0) * KDIM + kc8;
  const __bf16* gb1 = gb0 + (size_t)64 * KDIM;
  __bf16* la0 = As + wave * 512;         // wave-uniform LDS base (chunk = wave)
  __bf16* la1 = As + (wave + 4) * 512;
  __bf16* lb0 = Bs + wave * 512;
  __bf16* lb1 = Bs + (wave + 4) * 512;

  const int mbase = (wave >> 1) * 4;  // A chunk base: chunks 0-3 or 4-7
  const int nbase = (wave & 1) * 4;   // B chunk base
  const int lo8   = lane * 8;         // element offset within a chunk (16 B/lane)

  f32x4 acc[4][4] = {};

  for (int kt = 0; kt < KDIM / 32; ++kt) {
    const int k0 = kt * 32;
    async_ld16(ga0 + k0, la0);
    async_ld16(ga1 + k0, la1);
    async_ld16(gb0 + k0, lb0);
    async_ld16(gb1 + k0, lb1);
    __syncthreads();

    bf16x8 af[4], bfr[4];
#pragma unroll
    for (int mi = 0; mi < 4; ++mi)
      af[mi] = *(const bf16x8*)(As + (mbase + mi) * 512 + lo8);
#pragma unroll
    for (int ni = 0; ni < 4; ++ni)
      bfr[ni] = *(const bf16x8*)(Bs + (nbase + ni) * 512 + lo8);
#pragma unroll
    for (int mi = 0; mi < 4; ++mi)
#pragma unroll
      for (int ni = 0; ni < 4; ++ni)
        acc[mi][ni] = __builtin_amdgcn_mfma_f32_16x16x32_bf16(af[mi], bfr[ni],
                                                              acc[mi][ni], 0, 0, 0);
    __syncthreads();
  }

  // epilogue: D layout col=lane&15, row=(lane>>4)*4+reg
  const int waveM = (wave >> 1) * 64;
  const int waveN = (wave & 1) * 64;
  const int cl = lane & 15;
  const int rq = (lane >> 4) * 4;
#pragma unroll
  for (int ni = 0; ni < 4; ++ni) {
    const int gn = n0 + waveN + ni * 16 + cl;
    const float bb = bias[gn];
#pragma unroll
    for (int mi = 0; mi < 4; ++mi) {
      const int gm = m0 + waveM + mi * 16 + rq;
#pragma unroll
      for (int r = 0; r < 4; ++r)
        C[(size_t)(gm + r) * NOUT + gn] = (__bf16)(acc[mi][ni][r] + bb);
    }
  }
}

// ---------------- phase 2: per-token dots/norms/hash codes ----------------
// One block per token. Rows 0..31 = q heads, 32..39 = k heads. Rows 40..47 of
// As are uninitialized pad — they only feed MFMA output rows >= 40 which are
// discarded, so no zero-fill is needed.

__global__ void phase2_kernel(const __bf16* __restrict__ QK,
                              const __bf16* __restrict__ hwT,
                              float* __restrict__ out) {
  __shared__ __bf16 As[48][136];    // +8 bf16 pad -> conflict-free ds_read_b128
  __shared__ float code[40][129];   // (tanh+1)/2 codes, +1 pad
  __shared__ float rednorm[40];
  __shared__ float reddot[32];

  const int tid  = threadIdx.x;
  const int lane = tid & 63;
  const int wave = tid >> 6;
  const int b = blockIdx.x;

  // stage q,k rows (5120 bf16, contiguous) into padded LDS
  const __bf16* src = QK + (size_t)b * NOUT;
  for (int i = tid; i < 640; i += 256) {
    const int row = i >> 4;
    const int col = (i & 15) * 8;
    *(uint4*)(&As[row][col]) = *(const uint4*)(src + i * 8);
  }

  // B fragments (hash_w^T) straight from global — identical 32 KB for every
  // block, L2/L1-hot. Wave w owns n-tiles {w, w+4}.
  const int fr = lane & 15;
  const int fk = (lane >> 4) * 8;
  bf16x8 bf[2][4];
#pragma unroll
  for (int nn = 0; nn < 2; ++nn) {
    const int ni = wave + nn * 4;
#pragma unroll
    for (int ks = 0; ks < 4; ++ks)
      bf[nn][ks] = *(const bf16x8*)(hwT + (size_t)(ni * 16 + fr) * RB + ks * 32 + fk);
  }
  __syncthreads();

  // hash codes via MFMA: code[row][rbit] = sigmoid(2 * (In @ hwT^T))
#pragma unroll
  for (int mi = 0; mi < 3; ++mi) {
    bf16x8 af[4];
#pragma unroll
    for (int ks = 0; ks < 4; ++ks)
      af[ks] = *(const bf16x8*)(&As[mi * 16 + fr][ks * 32 + fk]);
#pragma unroll
    for (int nn = 0; nn < 2; ++nn) {
      const int ni = wave + nn * 4;
      f32x4 acc = {0.f, 0.f, 0.f, 0.f};
#pragma unroll
      for (int ks = 0; ks < 4; ++ks)
        acc = __builtin_amdgcn_mfma_f32_16x16x32_bf16(af[ks], bf[nn][ks], acc, 0, 0, 0);
      const int row0 = mi * 16 + (lane >> 4) * 4;
      const int col  = ni * 16 + (lane & 15);
#pragma unroll
      for (int r = 0; r < 4; ++r) {
        const int row = row0 + r;
        if (row < 40) code[row][col] = code_of(acc[r]);
      }
    }
  }

  // norms (tasks 0..39) and q·k dots (tasks 40..71), one wave per task
#pragma unroll
  for (int t = 0; t < 18; ++t) {
    const int task = wave + t * 4;
    float s;
    if (task < 40) {
      const float x0 = (float)As[task][lane * 2];
      const float x1 = (float)As[task][lane * 2 + 1];
      s = x0 * x0 + x1 * x1;
    } else {
      const int h  = task - 40;
      const int kr = 32 + (h >> 2);
      const float q0 = (float)As[h][lane * 2],  q1 = (float)As[h][lane * 2 + 1];
      const float k0 = (float)As[kr][lane * 2], k1 = (float)As[kr][lane * 2 + 1];
      s = q0 * k0 + q1 * k1;
    }
#pragma unroll
    for (int off = 32; off > 0; off >>= 1) s += __shfl_down(s, off);
    if (lane == 0) {
      if (task < 40) rednorm[task] = s; else reddot[task - 40] = s;
    }
  }
  __syncthreads();

  // final: thread (h, sub) sums 16 rbits of |qc - kc|, 8-thread shuffle reduce
  const int h   = tid >> 3;
  const int sub = tid & 7;
  const int kr  = 32 + (h >> 2);
  float s = 0.f;
#pragma unroll
  for (int j = 0; j < 16; ++j) {
    const int r = sub * 16 + j;
    s += fabsf(code[h][r] - code[kr][r]);
  }
  s += __shfl_down(s, 4, 8);
  s += __shfl_down(s, 2, 8);
  s += __shfl_down(s, 1, 8);
  if (sub == 0) {
    const float invsq = 0.08838834764831843f;  // 1/sqrt(128)
    out[(size_t)b * NH + h] = reddot[h] * invsq;
    const float hamw = (1.0f - s * (1.0f / 64.0f)) *
                       sqrtf(rednorm[h]) * sqrtf(rednorm[kr]) * invsq;
    out[(size_t)(B_TOK * NH) + (size_t)b * NH + h] = hamw;
  }
}

// ---------------- launch ----------------

extern "C" void kernel_launch(void* const* d_in, const int* in_sizes, int n_in,
                              void* d_out, int out_size, void* d_ws, size_t ws_size,
                              hipStream_t stream) {
  const float* hidden = (const float*)d_in[0];   // [8192][4096]
  const float* proj_w = (const float*)d_in[1];   // [4096][6144]
  const float* proj_b = (const float*)d_in[2];   // [6144]
  const float* hash_w = (const float*)d_in[3];   // [128][128]
  float* out = (float*)d_out;                    // [2*262144]

  char* w = (char*)d_ws;
  __bf16* Abf = (__bf16*)(w);                                     // 67,108,864 B
  __bf16* Wt  = (__bf16*)(w + 67108864);                          // 41,943,040 B
  __bf16* QK  = (__bf16*)(w + 67108864 + 41943040);               // 83,886,080 B
  __bf16* hwT = (__bf16*)(w + 67108864 + 41943040 + 83886080);    // 32,768 B

  conv_hidden_kernel<<<16384, 256, 0, stream>>>(hidden, Abf, (B_TOK * HID) / 8);
  conv_wt_kernel<<<dim3(NOUT / 32, KDIM / 32), dim3(32, 8), 0, stream>>>(proj_w, Wt);
  conv_hash_kernel<<<RB, DH, 0, stream>>>(hash_w, hwT);
  gemm_qk<<<dim3(NOUT / 128, B_TOK / 128), 256, 0, stream>>>(Abf, Wt, proj_b, QK);
  phase2_kernel<<<B_TOK, 256, 0, stream>>>(QK, hwT, out);
}

// Round 3
// 686.028 us; speedup vs baseline: 1.3689x; 1.3689x over previous
//
#include <hip/hip_runtime.h>
#include <hip/hip_bf16.h>
#include <cstdint>
#include <cstddef>

// Problem constants
#define B_TOK 8192
#define HID   4096
#define NH    32
#define NKV   8
#define DH    128
#define RB    128
#define KDIM  4096
#define NOUT  5120   // q (32*128) + k (8*128) columns; v columns are never used
#define QKVW  6144

typedef __bf16 bf16x8 __attribute__((ext_vector_type(8)));
typedef __bf16 bf16x4 __attribute__((ext_vector_type(4)));
typedef float  f32x4  __attribute__((ext_vector_type(4)));

// ---- async global->LDS, 16B per lane. LDS dest = wave-uniform base + lane*16 ----
__device__ __forceinline__ void async_ld16(const void* g, void* l) {
  __builtin_amdgcn_global_load_lds(
      (__attribute__((address_space(1))) void*)(g),
      (__attribute__((address_space(3))) void*)(l), 16, 0, 0);
}

// (tanh(x)+1)/2 == sigmoid(2x) = 1/(1+exp2(-2*log2e*x))
__device__ __forceinline__ float code_of(float x) {
  const float e = exp2f(x * -2.885390081777927f);
  return __builtin_amdgcn_rcpf(1.0f + e);
}

// ---------------- conversion kernels ----------------

__global__ void conv_hidden_kernel(const float* __restrict__ x,
                                   __bf16* __restrict__ y, int n8) {
  const int i = blockIdx.x * 256 + threadIdx.x;
  if (i >= n8) return;
  const float4 v0 = ((const float4*)x)[2 * i];
  const float4 v1 = ((const float4*)x)[2 * i + 1];
  bf16x8 o;
  o[0] = (__bf16)v0.x; o[1] = (__bf16)v0.y; o[2] = (__bf16)v0.z; o[3] = (__bf16)v0.w;
  o[4] = (__bf16)v1.x; o[5] = (__bf16)v1.y; o[6] = (__bf16)v1.z; o[7] = (__bf16)v1.w;
  ((bf16x8*)y)[i] = o;
}

// proj_w [4096][6144] -> Wt [5120][4096] bf16 (transpose of first 5120 cols)
// 64x64 tile per block: 5120 blocks (vs 20480 at 32x32), 32 mem ops/thread.
__global__ void conv_wt_kernel(const float* __restrict__ W, __bf16* __restrict__ Wt) {
  __shared__ float t[64][65];
  const int n0 = blockIdx.x * 64;   // over NOUT
  const int k0 = blockIdx.y * 64;   // over KDIM
  const int c  = threadIdx.x & 63;
  const int r0 = threadIdx.x >> 6;  // 0..3
#pragma unroll
  for (int j = 0; j < 16; ++j) {
    const int r = r0 + j * 4;
    t[r][c] = W[(size_t)(k0 + r) * QKVW + n0 + c];
  }
  __syncthreads();
#pragma unroll
  for (int j = 0; j < 16; ++j) {
    const int n = r0 + j * 4;
    // LDS read t[c][n]: bank = (65*c + n) % 32 = (c + n) % 32 -> 2-way, free
    Wt[(size_t)(n0 + n) * KDIM + k0 + c] = (__bf16)t[c][n];
  }
}

// hash_w [128][128] -> hwT [rbit][d] bf16
__global__ void conv_hash_kernel(const float* __restrict__ hw, __bf16* __restrict__ hwT) {
  const int r = blockIdx.x;    // rbit
  const int d = threadIdx.x;   // dim
  hwT[r * RB + d] = (__bf16)hw[(size_t)d * RB + r];
}

// ---------------- main GEMM: C[8192][5120] = A[8192][4096] @ Bt[5120][4096]^T + bias ----------------
// Round-1 structure (m97 ladder): global-side lanes contiguous (lane L -> row L>>2,
// col (L&3)*8 -> 4 fully-consumed 64B lines per 16-lane group). The resulting
// ~4 cyc/ds_read_b128 LDS conflict is the cheaper evil (round-2 evidence:
// fragment-order staging zeroed conflicts but quadrupled TA requests, +54% time).

__global__ void gemm_qk(const __bf16* __restrict__ A,
                        const __bf16* __restrict__ Bt,
                        const float* __restrict__ bias,
                        __bf16* __restrict__ C) {
  __shared__ __bf16 As[128 * 32];
  __shared__ __bf16 Bs[128 * 32];

  const int tid  = threadIdx.x;
  const int lane = tid & 63;
  const int wave = tid >> 6;
  const int m0 = blockIdx.y * 128;
  const int n0 = blockIdx.x * 128;
  const int waveM = (wave >> 1) * 64;
  const int waveN = (wave & 1) * 64;

  // staging decomposition: each global_load_lds covers 16 rows x 32 bf16
  const int srow  = lane >> 2;        // row within 16-row chunk
  const int selem = (lane & 3) * 8;   // element offset within 32-elem row

  const __bf16* ga0 = A + (size_t)(m0 + wave * 16 + srow) * KDIM + selem;
  const __bf16* ga1 = ga0 + (size_t)64 * KDIM;
  const __bf16* gb0 = Bt + (size_t)(n0 + wave * 16 + srow) * KDIM + selem;
  const __bf16* gb1 = gb0 + (size_t)64 * KDIM;
  __bf16* la0 = As + wave * 512;         // wave-uniform LDS base
  __bf16* la1 = As + (wave + 4) * 512;
  __bf16* lb0 = Bs + wave * 512;
  __bf16* lb1 = Bs + (wave + 4) * 512;

  const int fr = lane & 15;           // fragment row (m or n)
  const int fk = (lane >> 4) * 8;     // fragment k offset

  f32x4 acc[4][4] = {};

  for (int kt = 0; kt < KDIM / 32; ++kt) {
    const int k0 = kt * 32;
    async_ld16(ga0 + k0, la0);
    async_ld16(ga1 + k0, la1);
    async_ld16(gb0 + k0, lb0);
    async_ld16(gb1 + k0, lb1);
    __syncthreads();

    bf16x8 af[4], bfr[4];
#pragma unroll
    for (int mi = 0; mi < 4; ++mi)
      af[mi] = *(const bf16x8*)(As + (waveM + mi * 16 + fr) * 32 + fk);
#pragma unroll
    for (int ni = 0; ni < 4; ++ni)
      bfr[ni] = *(const bf16x8*)(Bs + (waveN + ni * 16 + fr) * 32 + fk);
#pragma unroll
    for (int mi = 0; mi < 4; ++mi)
#pragma unroll
      for (int ni = 0; ni < 4; ++ni)
        acc[mi][ni] = __builtin_amdgcn_mfma_f32_16x16x32_bf16(af[mi], bfr[ni],
                                                              acc[mi][ni], 0, 0, 0);
    __syncthreads();
  }

  // epilogue: D layout col=lane&15, row=(lane>>4)*4+reg
  const int cl = lane & 15;
  const int rq = (lane >> 4) * 4;
#pragma unroll
  for (int ni = 0; ni < 4; ++ni) {
    const int gn = n0 + waveN + ni * 16 + cl;
    const float bb = bias[gn];
#pragma unroll
    for (int mi = 0; mi < 4; ++mi) {
      const int gm = m0 + waveM + mi * 16 + rq;
#pragma unroll
      for (int r = 0; r < 4; ++r)
        C[(size_t)(gm + r) * NOUT + gn] = (__bf16)(acc[mi][ni][r] + bb);
    }
  }
}

// ---------------- phase 2: per-token dots/norms/hash codes ----------------
// One block per token. Rows 0..31 = q heads, 32..39 = k heads. Rows 40..47 of
// As are uninitialized pad — they only feed MFMA outputs that are discarded.
// Norms and q.k dots computed as Gram-matrix MFMA tiles: for 16x16x32 the
// B-fragment lane map equals the A-fragment map, so mfma(af_i, af_j) gives
// D[m][n] = row(16i+m) . row(16j+n).

__global__ void phase2_kernel(const __bf16* __restrict__ QK,
                              const __bf16* __restrict__ hwT,
                              float* __restrict__ out) {
  __shared__ __bf16 As[48][136];    // +8 bf16 pad -> conflict-free ds_read_b128
  __shared__ float code[40][129];   // (tanh+1)/2 codes, +1 pad
  __shared__ float rednorm[40];
  __shared__ float reddot[32];

  const int tid  = threadIdx.x;
  const int lane = tid & 63;
  const int wave = tid >> 6;
  const int b = blockIdx.x;

  // stage q,k rows (5120 bf16, contiguous) into padded LDS
  const __bf16* src = QK + (size_t)b * NOUT;
  for (int i = tid; i < 640; i += 256) {
    const int row = i >> 4;
    const int col = (i & 15) * 8;
    *(uint4*)(&As[row][col]) = *(const uint4*)(src + i * 8);
  }

  // B fragments (hash_w^T) straight from global — identical 32 KB for every
  // block, L1/L2-hot. Wave w owns n-tiles {w, w+4}.
  const int fr = lane & 15;
  const int fk = (lane >> 4) * 8;
  bf16x8 bf[2][4];
#pragma unroll
  for (int nn = 0; nn < 2; ++nn) {
    const int ni = wave + nn * 4;
#pragma unroll
    for (int ks = 0; ks < 4; ++ks)
      bf[nn][ks] = *(const bf16x8*)(hwT + (size_t)(ni * 16 + fr) * RB + ks * 32 + fk);
  }
  __syncthreads();

  // hash codes via MFMA: code[row][rbit] = sigmoid(2 * (In @ hwT^T))
#pragma unroll
  for (int mi = 0; mi < 3; ++mi) {
    bf16x8 af[4];
#pragma unroll
    for (int ks = 0; ks < 4; ++ks)
      af[ks] = *(const bf16x8*)(&As[mi * 16 + fr][ks * 32 + fk]);
#pragma unroll
    for (int nn = 0; nn < 2; ++nn) {
      const int ni = wave + nn * 4;
      f32x4 acc = {0.f, 0.f, 0.f, 0.f};
#pragma unroll
      for (int ks = 0; ks < 4; ++ks)
        acc = __builtin_amdgcn_mfma_f32_16x16x32_bf16(af[ks], bf[nn][ks], acc, 0, 0, 0);
      const int row0 = mi * 16 + (lane >> 4) * 4;
      const int col  = ni * 16 + (lane & 15);
#pragma unroll
      for (int r = 0; r < 4; ++r) {
        const int row = row0 + r;
        if (row < 40) code[row][col] = code_of(acc[r]);
      }
    }
  }

  // Gram tiles: wave0 -> (0,0) + (2,2); wave1 -> (1,1); wave2 -> (0,2); wave3 -> (1,2)
  {
    const int q = lane >> 4;
    const int c = lane & 15;
    const int ti = (wave == 1 || wave == 3) ? 1 : 0;
    const int tj = (wave >= 2) ? 2 : ti;
    bf16x8 fa[4], fb[4];
#pragma unroll
    for (int ks = 0; ks < 4; ++ks) {
      fa[ks] = *(const bf16x8*)(&As[ti * 16 + fr][ks * 32 + fk]);
      fb[ks] = *(const bf16x8*)(&As[tj * 16 + fr][ks * 32 + fk]);
    }
    f32x4 g = {0.f, 0.f, 0.f, 0.f};
#pragma unroll
    for (int ks = 0; ks < 4; ++ks)
      g = __builtin_amdgcn_mfma_f32_16x16x32_bf16(fa[ks], fb[ks], g, 0, 0, 0);
    if (ti == tj) {
      // diag: D[m][m], m = q*4+r == c  ->  lane with c>>2 == q holds it at r=c&3
      if ((c >> 2) == q) rednorm[ti * 16 + c] = g[c & 3];
    } else {
      // dot tile (ti,2): need D[h mod 16][h>>2 - ti*... ] -> col c == ti*4 + q
      if (c == ti * 4 + q) {
#pragma unroll
        for (int r = 0; r < 4; ++r) reddot[ti * 16 + q * 4 + r] = g[r];
      }
    }
    if (wave == 0) {  // second tile: (2,2) for k-norms (rows 32..39)
      bf16x8 fc[4];
#pragma unroll
      for (int ks = 0; ks < 4; ++ks)
        fc[ks] = *(const bf16x8*)(&As[32 + fr][ks * 32 + fk]);
      f32x4 g2 = {0.f, 0.f, 0.f, 0.f};
#pragma unroll
      for (int ks = 0; ks < 4; ++ks)
        g2 = __builtin_amdgcn_mfma_f32_16x16x32_bf16(fc[ks], fc[ks], g2, 0, 0, 0);
      if ((c >> 2) == q && c < 8) rednorm[32 + c] = g2[c & 3];
    }
  }
  __syncthreads();

  // final: thread (h, sub) sums 16 rbits of |qc - kc|, 8-thread shuffle reduce
  const int h   = tid >> 3;
  const int sub = tid & 7;
  const int kr  = 32 + (h >> 2);
  float s = 0.f;
#pragma unroll
  for (int j = 0; j < 16; ++j) {
    const int r = sub * 16 + j;
    s += fabsf(code[h][r] - code[kr][r]);
  }
  s += __shfl_down(s, 4, 8);
  s += __shfl_down(s, 2, 8);
  s += __shfl_down(s, 1, 8);
  if (sub == 0) {
    const float invsq = 0.08838834764831843f;  // 1/sqrt(128)
    out[(size_t)b * NH + h] = reddot[h] * invsq;
    const float hamw = (1.0f - s * (1.0f / 64.0f)) *
                       sqrtf(rednorm[h]) * sqrtf(rednorm[kr]) * invsq;
    out[(size_t)(B_TOK * NH) + (size_t)b * NH + h] = hamw;
  }
}

// ---------------- launch ----------------

extern "C" void kernel_launch(void* const* d_in, const int* in_sizes, int n_in,
                              void* d_out, int out_size, void* d_ws, size_t ws_size,
                              hipStream_t stream) {
  const float* hidden = (const float*)d_in[0];   // [8192][4096]
  const float* proj_w = (const float*)d_in[1];   // [4096][6144]
  const float* proj_b = (const float*)d_in[2];   // [6144]
  const float* hash_w = (const float*)d_in[3];   // [128][128]
  float* out = (float*)d_out;                    // [2*262144]

  char* w = (char*)d_ws;
  __bf16* Abf = (__bf16*)(w);                                     // 67,108,864 B
  __bf16* Wt  = (__bf16*)(w + 67108864);                          // 41,943,040 B
  __bf16* QK  = (__bf16*)(w + 67108864 + 41943040);               // 83,886,080 B
  __bf16* hwT = (__bf16*)(w + 67108864 + 41943040 + 83886080);    // 32,768 B

  conv_hidden_kernel<<<16384, 256, 0, stream>>>(hidden, Abf, (B_TOK * HID) / 8);
  conv_wt_kernel<<<dim3(NOUT / 64, KDIM / 64), dim3(256), 0, stream>>>(proj_w, Wt);
  conv_hash_kernel<<<RB, DH, 0, stream>>>(hash_w, hwT);
  gemm_qk<<<dim3(NOUT / 128, B_TOK / 128), 256, 0, stream>>>(Abf, Wt, proj_b, QK);
  phase2_kernel<<<B_TOK, 256, 0, stream>>>(QK, hwT, out);
}

// Round 4
// 685.010 us; speedup vs baseline: 1.3709x; 1.0015x over previous
//
#include <hip/hip_runtime.h>
#include <hip/hip_bf16.h>
#include <cstdint>
#include <cstddef>

// Problem constants
#define B_TOK 8192
#define HID   4096
#define NH    32
#define NKV   8
#define DH    128
#define RB    128
#define KDIM  4096
#define NOUT  5120   // q (32*128) + k (8*128) columns; v columns are never used
#define QKVW  6144

typedef __bf16 bf16x8 __attribute__((ext_vector_type(8)));
typedef __bf16 bf16x4 __attribute__((ext_vector_type(4)));
typedef float  f32x4  __attribute__((ext_vector_type(4)));

// ---- async global->LDS, 16B per lane. LDS dest = wave-uniform base + lane*16 ----
__device__ __forceinline__ void async_ld16(const void* g, void* l) {
  __builtin_amdgcn_global_load_lds(
      (__attribute__((address_space(1))) void*)(g),
      (__attribute__((address_space(3))) void*)(l), 16, 0, 0);
}

// (tanh(x)+1)/2 == sigmoid(2x) = 1/(1+exp2(-2*log2e*x))
__device__ __forceinline__ float code_of(float x) {
  const float e = exp2f(x * -2.885390081777927f);
  return __builtin_amdgcn_rcpf(1.0f + e);
}

// ---------------- fused prep kernel ----------------
// Block partition: [0,16384) hidden fp32->bf16; [16384,21504) proj_w transpose
// 64x64 tiles; [21504,21568) hash_w transpose. Branches are block-uniform.

#define NB_HID  16384
#define NB_WT   5120   // 80 n-tiles x 64 k-tiles
#define NB_HASH 64

__global__ void prep_kernel(const float* __restrict__ hidden, __bf16* __restrict__ Abf,
                            const float* __restrict__ W, __bf16* __restrict__ Wt,
                            const float* __restrict__ hw, __bf16* __restrict__ hwT) {
  __shared__ float t[64][65];
  const int bx  = blockIdx.x;
  const int tid = threadIdx.x;

  if (bx < NB_HID) {
    const int i = bx * 256 + tid;   // i < 4,194,304 always (16384*256)
    const float4 v0 = ((const float4*)hidden)[2 * i];
    const float4 v1 = ((const float4*)hidden)[2 * i + 1];
    bf16x8 o;
    o[0] = (__bf16)v0.x; o[1] = (__bf16)v0.y; o[2] = (__bf16)v0.z; o[3] = (__bf16)v0.w;
    o[4] = (__bf16)v1.x; o[5] = (__bf16)v1.y; o[6] = (__bf16)v1.z; o[7] = (__bf16)v1.w;
    ((bf16x8*)Abf)[i] = o;
  } else if (bx < NB_HID + NB_WT) {
    const int bt = bx - NB_HID;
    const int n0 = (bt % 80) * 64;   // over NOUT
    const int k0 = (bt / 80) * 64;   // over KDIM
    const int c  = tid & 63;
    const int r0 = tid >> 6;         // 0..3
#pragma unroll
    for (int j = 0; j < 16; ++j) {
      const int r = r0 + j * 4;
      t[r][c] = W[(size_t)(k0 + r) * QKVW + n0 + c];
    }
    __syncthreads();
#pragma unroll
    for (int j = 0; j < 16; ++j) {
      const int n = r0 + j * 4;
      // LDS read t[c][n]: bank = (c + n) % 32 -> 2-way, free
      Wt[(size_t)(n0 + n) * KDIM + k0 + c] = (__bf16)t[c][n];
    }
  } else {
    const int idx = (bx - NB_HID - NB_WT) * 256 + tid;  // 16384 elems
    const int r = idx >> 7;    // rbit
    const int d = idx & 127;   // dim
    hwT[r * RB + d] = (__bf16)hw[(size_t)d * RB + r];   // write coalesced
  }
}

// ---------------- main GEMM: C[8192][5120] = A[8192][4096] @ Bt[5120][4096]^T + bias ----------------
// m97-ladder structure (431 us / 798 GF/s = the known source-level plateau).
// Global-side lanes contiguous (4 fully-consumed 64B lines per 16-lane group);
// the resulting ~4cyc/ds_read_b128 LDS conflict is overlapped with MFMA and is
// the cheaper evil (round-2 evidence: fragment-order staging zeroed conflicts
// but quadrupled TA requests, +54% time).

__global__ void gemm_qk(const __bf16* __restrict__ A,
                        const __bf16* __restrict__ Bt,
                        const float* __restrict__ bias,
                        __bf16* __restrict__ C) {
  __shared__ __bf16 As[128 * 32];
  __shared__ __bf16 Bs[128 * 32];

  const int tid  = threadIdx.x;
  const int lane = tid & 63;
  const int wave = tid >> 6;
  const int m0 = blockIdx.y * 128;
  const int n0 = blockIdx.x * 128;
  const int waveM = (wave >> 1) * 64;
  const int waveN = (wave & 1) * 64;

  // staging decomposition: each global_load_lds covers 16 rows x 32 bf16
  const int srow  = lane >> 2;        // row within 16-row chunk
  const int selem = (lane & 3) * 8;   // element offset within 32-elem row

  const __bf16* ga0 = A + (size_t)(m0 + wave * 16 + srow) * KDIM + selem;
  const __bf16* ga1 = ga0 + (size_t)64 * KDIM;
  const __bf16* gb0 = Bt + (size_t)(n0 + wave * 16 + srow) * KDIM + selem;
  const __bf16* gb1 = gb0 + (size_t)64 * KDIM;
  __bf16* la0 = As + wave * 512;         // wave-uniform LDS base
  __bf16* la1 = As + (wave + 4) * 512;
  __bf16* lb0 = Bs + wave * 512;
  __bf16* lb1 = Bs + (wave + 4) * 512;

  const int fr = lane & 15;           // fragment row (m or n)
  const int fk = (lane >> 4) * 8;     // fragment k offset

  f32x4 acc[4][4] = {};

  for (int kt = 0; kt < KDIM / 32; ++kt) {
    const int k0 = kt * 32;
    async_ld16(ga0 + k0, la0);
    async_ld16(ga1 + k0, la1);
    async_ld16(gb0 + k0, lb0);
    async_ld16(gb1 + k0, lb1);
    __syncthreads();

    bf16x8 af[4], bfr[4];
#pragma unroll
    for (int mi = 0; mi < 4; ++mi)
      af[mi] = *(const bf16x8*)(As + (waveM + mi * 16 + fr) * 32 + fk);
#pragma unroll
    for (int ni = 0; ni < 4; ++ni)
      bfr[ni] = *(const bf16x8*)(Bs + (waveN + ni * 16 + fr) * 32 + fk);
#pragma unroll
    for (int mi = 0; mi < 4; ++mi)
#pragma unroll
      for (int ni = 0; ni < 4; ++ni)
        acc[mi][ni] = __builtin_amdgcn_mfma_f32_16x16x32_bf16(af[mi], bfr[ni],
                                                              acc[mi][ni], 0, 0, 0);
    __syncthreads();
  }

  // epilogue: D layout col=lane&15, row=(lane>>4)*4+reg
  const int cl = lane & 15;
  const int rq = (lane >> 4) * 4;
#pragma unroll
  for (int ni = 0; ni < 4; ++ni) {
    const int gn = n0 + waveN + ni * 16 + cl;
    const float bb = bias[gn];
#pragma unroll
    for (int mi = 0; mi < 4; ++mi) {
      const int gm = m0 + waveM + mi * 16 + rq;
#pragma unroll
      for (int r = 0; r < 4; ++r)
        C[(size_t)(gm + r) * NOUT + gn] = (__bf16)(acc[mi][ni][r] + bb);
    }
  }
}

// ---------------- phase 2: per-token dots/norms/hash codes ----------------
// One block per token. Rows 0..31 = q heads, 32..39 = k heads. Rows 40..47 of
// As are uninitialized pad — they only feed MFMA outputs that are discarded.
// code LDS leading dim = 132 floats; Hamming loop walks cols with stride 8
// (c = sub + 8j) -> q-read bank = (4h+sub+8j)%32, exactly 2 lanes/bank = free
// (old layout was a structural 4-way: 16*sub mod 32 collapses to {0,16}).

__global__ void phase2_kernel(const __bf16* __restrict__ QK,
                              const __bf16* __restrict__ hwT,
                              float* __restrict__ out) {
  __shared__ __bf16 As[48][136];    // +8 bf16 pad -> conflict-free ds_read_b128
  __shared__ float code[40][132];   // (tanh+1)/2 codes
  __shared__ float rednorm[40];
  __shared__ float reddot[32];

  const int tid  = threadIdx.x;
  const int lane = tid & 63;
  const int wave = tid >> 6;
  const int b = blockIdx.x;

  // stage q,k rows (5120 bf16, contiguous) into padded LDS
  const __bf16* src = QK + (size_t)b * NOUT;
  for (int i = tid; i < 640; i += 256) {
    const int row = i >> 4;
    const int col = (i & 15) * 8;
    *(uint4*)(&As[row][col]) = *(const uint4*)(src + i * 8);
  }

  // B fragments (hash_w^T) straight from global — identical 32 KB for every
  // block, L1/L2-hot. Wave w owns n-tiles {w, w+4}.
  const int fr = lane & 15;
  const int fk = (lane >> 4) * 8;
  bf16x8 bf[2][4];
#pragma unroll
  for (int nn = 0; nn < 2; ++nn) {
    const int ni = wave + nn * 4;
#pragma unroll
    for (int ks = 0; ks < 4; ++ks)
      bf[nn][ks] = *(const bf16x8*)(hwT + (size_t)(ni * 16 + fr) * RB + ks * 32 + fk);
  }
  __syncthreads();

  // hash codes via MFMA: code[row][rbit] = sigmoid(2 * (In @ hwT^T))
#pragma unroll
  for (int mi = 0; mi < 3; ++mi) {
    bf16x8 af[4];
#pragma unroll
    for (int ks = 0; ks < 4; ++ks)
      af[ks] = *(const bf16x8*)(&As[mi * 16 + fr][ks * 32 + fk]);
#pragma unroll
    for (int nn = 0; nn < 2; ++nn) {
      const int ni = wave + nn * 4;
      f32x4 acc = {0.f, 0.f, 0.f, 0.f};
#pragma unroll
      for (int ks = 0; ks < 4; ++ks)
        acc = __builtin_amdgcn_mfma_f32_16x16x32_bf16(af[ks], bf[nn][ks], acc, 0, 0, 0);
      const int row0 = mi * 16 + (lane >> 4) * 4;
      const int col  = ni * 16 + (lane & 15);
#pragma unroll
      for (int r = 0; r < 4; ++r) {
        const int row = row0 + r;
        // write bank = (16q + 4r + c) % 32 per instr -> 2-way, free
        if (row < 40) code[row][col] = code_of(acc[r]);
      }
    }
  }

  // Gram tiles: wave0 -> (0,0) + (2,2); wave1 -> (1,1); wave2 -> (0,2); wave3 -> (1,2)
  {
    const int q = lane >> 4;
    const int c = lane & 15;
    const int ti = (wave == 1 || wave == 3) ? 1 : 0;
    const int tj = (wave >= 2) ? 2 : ti;
    bf16x8 fa[4], fb[4];
#pragma unroll
    for (int ks = 0; ks < 4; ++ks) {
      fa[ks] = *(const bf16x8*)(&As[ti * 16 + fr][ks * 32 + fk]);
      fb[ks] = *(const bf16x8*)(&As[tj * 16 + fr][ks * 32 + fk]);
    }
    f32x4 g = {0.f, 0.f, 0.f, 0.f};
#pragma unroll
    for (int ks = 0; ks < 4; ++ks)
      g = __builtin_amdgcn_mfma_f32_16x16x32_bf16(fa[ks], fb[ks], g, 0, 0, 0);
    if (ti == tj) {
      // diag: D[m][m], m = q*4+r == c  ->  lane with c>>2 == q holds it at r=c&3
      if ((c >> 2) == q) rednorm[ti * 16 + c] = g[c & 3];
    } else {
      // dot tile (ti,2): rows h (q side), cols = k index; need col c == ti*4 + q
      if (c == ti * 4 + q) {
#pragma unroll
        for (int r = 0; r < 4; ++r) reddot[ti * 16 + q * 4 + r] = g[r];
      }
    }
    if (wave == 0) {  // second tile: (2,2) for k-norms (rows 32..39)
      bf16x8 fc[4];
#pragma unroll
      for (int ks = 0; ks < 4; ++ks)
        fc[ks] = *(const bf16x8*)(&As[32 + fr][ks * 32 + fk]);
      f32x4 g2 = {0.f, 0.f, 0.f, 0.f};
#pragma unroll
      for (int ks = 0; ks < 4; ++ks)
        g2 = __builtin_amdgcn_mfma_f32_16x16x32_bf16(fc[ks], fc[ks], g2, 0, 0, 0);
      if ((c >> 2) == q && c < 8) rednorm[32 + c] = g2[c & 3];
    }
  }
  __syncthreads();

  // final: thread (h, sub) sums |qc-kc| over cols c = sub + 8j (stride-8 walk),
  // 8-thread shuffle reduce. k-row reads: 16 distinct addrs/wave, broadcast to
  // 4 lanes each, banks 2-deep max = free.
  const int h   = tid >> 3;
  const int sub = tid & 7;
  const int kr  = 32 + (h >> 2);
  float s = 0.f;
#pragma unroll
  for (int j = 0; j < 16; ++j) {
    const int c = sub + 8 * j;
    s += fabsf(code[h][c] - code[kr][c]);
  }
  s += __shfl_down(s, 4, 8);
  s += __shfl_down(s, 2, 8);
  s += __shfl_down(s, 1, 8);
  if (sub == 0) {
    const float invsq = 0.08838834764831843f;  // 1/sqrt(128)
    out[(size_t)b * NH + h] = reddot[h] * invsq;
    const float hamw = (1.0f - s * (1.0f / 64.0f)) *
                       sqrtf(rednorm[h]) * sqrtf(rednorm[kr]) * invsq;
    out[(size_t)(B_TOK * NH) + (size_t)b * NH + h] = hamw;
  }
}

// ---------------- launch ----------------

extern "C" void kernel_launch(void* const* d_in, const int* in_sizes, int n_in,
                              void* d_out, int out_size, void* d_ws, size_t ws_size,
                              hipStream_t stream) {
  const float* hidden = (const float*)d_in[0];   // [8192][4096]
  const float* proj_w = (const float*)d_in[1];   // [4096][6144]
  const float* proj_b = (const float*)d_in[2];   // [6144]
  const float* hash_w = (const float*)d_in[3];   // [128][128]
  float* out = (float*)d_out;                    // [2*262144]

  char* w = (char*)d_ws;
  __bf16* Abf = (__bf16*)(w);                                     // 67,108,864 B
  __bf16* Wt  = (__bf16*)(w + 67108864);                          // 41,943,040 B
  __bf16* QK  = (__bf16*)(w + 67108864 + 41943040);               // 83,886,080 B
  __bf16* hwT = (__bf16*)(w + 67108864 + 41943040 + 83886080);    // 32,768 B

  prep_kernel<<<NB_HID + NB_WT + NB_HASH, 256, 0, stream>>>(hidden, Abf, proj_w, Wt,
                                                            hash_w, hwT);
  gemm_qk<<<dim3(NOUT / 128, B_TOK / 128), 256, 0, stream>>>(Abf, Wt, proj_b, QK);
  phase2_kernel<<<B_TOK, 256, 0, stream>>>(QK, hwT, out);
}

// Round 5
// 630.676 us; speedup vs baseline: 1.4890x; 1.0862x over previous
//
#include <hip/hip_runtime.h>
#include <hip/hip_bf16.h>
#include <cstdint>
#include <cstddef>

// Problem constants
#define B_TOK 8192
#define HID   4096
#define NH    32
#define NKV   8
#define DH    128
#define RB    128
#define KDIM  4096
#define NOUT  5120   // q (32*128) + k (8*128) columns; v columns are never used
#define QKVW  6144

typedef __bf16 bf16x8 __attribute__((ext_vector_type(8)));
typedef __bf16 bf16x4 __attribute__((ext_vector_type(4)));
typedef float  f32x4  __attribute__((ext_vector_type(4)));

// ---- async global->LDS, 16B per lane. LDS dest = wave-uniform base + lane*16 ----
__device__ __forceinline__ void async_ld16(const void* g, void* l) {
  __builtin_amdgcn_global_load_lds(
      (__attribute__((address_space(1))) void*)(g),
      (__attribute__((address_space(3))) void*)(l), 16, 0, 0);
}

// (tanh(x)+1)/2 == sigmoid(2x) = 1/(1+exp2(-2*log2e*x))
__device__ __forceinline__ float code_of(float x) {
  const float e = exp2f(x * -2.885390081777927f);
  return __builtin_amdgcn_rcpf(1.0f + e);
}

// ---------------- fused prep kernel ----------------
// Block partition: [0,16384) hidden fp32->bf16; [16384,21504) proj_w transpose
// 64x64 tiles; [21504,21568) hash_w transpose. Branches are block-uniform.

#define NB_HID  16384
#define NB_WT   5120   // 80 n-tiles x 64 k-tiles
#define NB_HASH 64

__global__ void prep_kernel(const float* __restrict__ hidden, __bf16* __restrict__ Abf,
                            const float* __restrict__ W, __bf16* __restrict__ Wt,
                            const float* __restrict__ hw, __bf16* __restrict__ hwT) {
  __shared__ float t[64][65];
  const int bx  = blockIdx.x;
  const int tid = threadIdx.x;

  if (bx < NB_HID) {
    const int i = bx * 256 + tid;   // i < 4,194,304 always (16384*256)
    const float4 v0 = ((const float4*)hidden)[2 * i];
    const float4 v1 = ((const float4*)hidden)[2 * i + 1];
    bf16x8 o;
    o[0] = (__bf16)v0.x; o[1] = (__bf16)v0.y; o[2] = (__bf16)v0.z; o[3] = (__bf16)v0.w;
    o[4] = (__bf16)v1.x; o[5] = (__bf16)v1.y; o[6] = (__bf16)v1.z; o[7] = (__bf16)v1.w;
    ((bf16x8*)Abf)[i] = o;
  } else if (bx < NB_HID + NB_WT) {
    const int bt = bx - NB_HID;
    const int n0 = (bt % 80) * 64;   // over NOUT
    const int k0 = (bt / 80) * 64;   // over KDIM
    // loads: float4-vectorized, 4 iters (vs 16 scalar): wave reads 4x256B rows
    const int c4 = tid & 15;
    const int rr = tid >> 4;         // 0..15
#pragma unroll
    for (int j = 0; j < 4; ++j) {
      const int r = rr + j * 16;
      const float4 v = *(const float4*)&W[(size_t)(k0 + r) * QKVW + n0 + c4 * 4];
      t[r][c4 * 4 + 0] = v.x; t[r][c4 * 4 + 1] = v.y;
      t[r][c4 * 4 + 2] = v.z; t[r][c4 * 4 + 3] = v.w;
    }
    __syncthreads();
    // stores: pack 8 k-values -> one 16B store. LDS read bank = (8*c8+i+n)%32,
    // per instr i: {0,8,16,24}+n(0..7) covers each bank 2x -> free.
    const int c8 = tid & 7;
    const int nn = tid >> 3;         // 0..31
#pragma unroll
    for (int jj = 0; jj < 2; ++jj) {
      const int n = nn + jj * 32;
      bf16x8 o;
#pragma unroll
      for (int i = 0; i < 8; ++i) o[i] = (__bf16)t[c8 * 8 + i][n];
      *(bf16x8*)&Wt[(size_t)(n0 + n) * KDIM + k0 + c8 * 8] = o;
    }
  } else {
    const int idx = (bx - NB_HID - NB_WT) * 256 + tid;  // 16384 elems
    const int r = idx >> 7;    // rbit
    const int d = idx & 127;   // dim
    hwT[r * RB + d] = (__bf16)hw[(size_t)d * RB + r];   // write coalesced
  }
}

// ---------------- main GEMM: C[8192][5120] = A[8192][4096] @ Bt[5120][4096]^T + bias ----------------
// m97-ladder structure, extended:
//  * BK=64 as TWO 32-k sub-tiles (identical DMA/fragment patterns per sub-tile;
//    LDS 32KB, still 4 blocks/CU VGPR-limited) -> barrier count halved 128->64,
//    32 MFMAs amortize each vmcnt(0)+barrier drain.
//  * XCD swizzle: lin%8 -> xcd; each XCD owns a 5-wide n-strip so its Wt
//    working set is ~5MB ~= L2 -> staging B-loads become L2 hits, shortening
//    the drain (L2 ~200cyc vs HBM ~900cyc).
// Global-side lanes stay contiguous (round-2 lesson: scatter kills the TA);
// the ~4cyc/ds_read_b128 LDS conflict remains the accepted cheaper evil.

__global__ void gemm_qk(const __bf16* __restrict__ A,
                        const __bf16* __restrict__ Bt,
                        const float* __restrict__ bias,
                        __bf16* __restrict__ C) {
  __shared__ __bf16 As[2][128 * 32];
  __shared__ __bf16 Bs[2][128 * 32];

  const int tid  = threadIdx.x;
  const int lane = tid & 63;
  const int wave = tid >> 6;

  // XCD-aware swizzle (bijective on 40x64 grid)
  const int lin = blockIdx.y * 40 + blockIdx.x;
  const int xcd = lin & 7;
  const int seq = lin >> 3;          // 0..319 per XCD
  const int n0 = (xcd * 5 + (seq % 5)) * 128;
  const int m0 = (seq / 5) * 128;

  const int waveM = (wave >> 1) * 64;
  const int waveN = (wave & 1) * 64;

  // staging decomposition: each global_load_lds covers 16 rows x 32 bf16
  const int srow  = lane >> 2;        // row within 16-row chunk
  const int selem = (lane & 3) * 8;   // element offset within 32-elem row

  const __bf16* ga0 = A + (size_t)(m0 + wave * 16 + srow) * KDIM + selem;
  const __bf16* ga1 = ga0 + (size_t)64 * KDIM;
  const __bf16* gb0 = Bt + (size_t)(n0 + wave * 16 + srow) * KDIM + selem;
  const __bf16* gb1 = gb0 + (size_t)64 * KDIM;
  __bf16* la0 = &As[0][wave * 512];         // wave-uniform LDS bases
  __bf16* la1 = &As[0][(wave + 4) * 512];
  __bf16* lb0 = &Bs[0][wave * 512];
  __bf16* lb1 = &Bs[0][(wave + 4) * 512];
  __bf16* la0b = &As[1][wave * 512];
  __bf16* la1b = &As[1][(wave + 4) * 512];
  __bf16* lb0b = &Bs[1][wave * 512];
  __bf16* lb1b = &Bs[1][(wave + 4) * 512];

  const int fr = lane & 15;           // fragment row (m or n)
  const int fk = (lane >> 4) * 8;     // fragment k offset

  f32x4 acc[4][4] = {};

  for (int kt = 0; kt < KDIM / 64; ++kt) {
    const int k0 = kt * 64;
    async_ld16(ga0 + k0, la0);  async_ld16(ga0 + k0 + 32, la0b);
    async_ld16(ga1 + k0, la1);  async_ld16(ga1 + k0 + 32, la1b);
    async_ld16(gb0 + k0, lb0);  async_ld16(gb0 + k0 + 32, lb0b);
    async_ld16(gb1 + k0, lb1);  async_ld16(gb1 + k0 + 32, lb1b);
    __syncthreads();

#pragma unroll
    for (int ks = 0; ks < 2; ++ks) {
      bf16x8 af[4], bfr[4];
#pragma unroll
      for (int mi = 0; mi < 4; ++mi)
        af[mi] = *(const bf16x8*)(&As[ks][(waveM + mi * 16 + fr) * 32 + fk]);
#pragma unroll
      for (int ni = 0; ni < 4; ++ni)
        bfr[ni] = *(const bf16x8*)(&Bs[ks][(waveN + ni * 16 + fr) * 32 + fk]);
#pragma unroll
      for (int mi = 0; mi < 4; ++mi)
#pragma unroll
        for (int ni = 0; ni < 4; ++ni)
          acc[mi][ni] = __builtin_amdgcn_mfma_f32_16x16x32_bf16(af[mi], bfr[ni],
                                                                acc[mi][ni], 0, 0, 0);
    }
    __syncthreads();
  }

  // epilogue: D layout col=lane&15, row=(lane>>4)*4+reg
  const int cl = lane & 15;
  const int rq = (lane >> 4) * 4;
#pragma unroll
  for (int ni = 0; ni < 4; ++ni) {
    const int gn = n0 + waveN + ni * 16 + cl;
    const float bb = bias[gn];
#pragma unroll
    for (int mi = 0; mi < 4; ++mi) {
      const int gm = m0 + waveM + mi * 16 + rq;
#pragma unroll
      for (int r = 0; r < 4; ++r)
        C[(size_t)(gm + r) * NOUT + gn] = (__bf16)(acc[mi][ni][r] + bb);
    }
  }
}

// ---------------- phase 2: per-token dots/norms/hash codes ----------------
// One block per token. Rows 0..31 = q heads, 32..39 = k heads. Rows 40..47 of
// As are uninitialized pad — they only feed MFMA outputs that are discarded.

__global__ void phase2_kernel(const __bf16* __restrict__ QK,
                              const __bf16* __restrict__ hwT,
                              float* __restrict__ out) {
  __shared__ __bf16 As[48][136];    // +8 bf16 pad -> conflict-free ds_read_b128
  __shared__ float code[40][132];   // (tanh+1)/2 codes
  __shared__ float rednorm[40];
  __shared__ float reddot[32];

  const int tid  = threadIdx.x;
  const int lane = tid & 63;
  const int wave = tid >> 6;
  const int b = blockIdx.x;

  // stage q,k rows (5120 bf16, contiguous) into padded LDS
  const __bf16* src = QK + (size_t)b * NOUT;
  for (int i = tid; i < 640; i += 256) {
    const int row = i >> 4;
    const int col = (i & 15) * 8;
    *(uint4*)(&As[row][col]) = *(const uint4*)(src + i * 8);
  }

  // B fragments (hash_w^T) straight from global — identical 32 KB for every
  // block, L1/L2-hot. Wave w owns n-tiles {w, w+4}.
  const int fr = lane & 15;
  const int fk = (lane >> 4) * 8;
  bf16x8 bf[2][4];
#pragma unroll
  for (int nn = 0; nn < 2; ++nn) {
    const int ni = wave + nn * 4;
#pragma unroll
    for (int ks = 0; ks < 4; ++ks)
      bf[nn][ks] = *(const bf16x8*)(hwT + (size_t)(ni * 16 + fr) * RB + ks * 32 + fk);
  }
  __syncthreads();

  // hash codes via MFMA: code[row][rbit] = sigmoid(2 * (In @ hwT^T))
#pragma unroll
  for (int mi = 0; mi < 3; ++mi) {
    bf16x8 af[4];
#pragma unroll
    for (int ks = 0; ks < 4; ++ks)
      af[ks] = *(const bf16x8*)(&As[mi * 16 + fr][ks * 32 + fk]);
#pragma unroll
    for (int nn = 0; nn < 2; ++nn) {
      const int ni = wave + nn * 4;
      f32x4 acc = {0.f, 0.f, 0.f, 0.f};
#pragma unroll
      for (int ks = 0; ks < 4; ++ks)
        acc = __builtin_amdgcn_mfma_f32_16x16x32_bf16(af[ks], bf[nn][ks], acc, 0, 0, 0);
      const int row0 = mi * 16 + (lane >> 4) * 4;
      const int col  = ni * 16 + (lane & 15);
#pragma unroll
      for (int r = 0; r < 4; ++r) {
        const int row = row0 + r;
        if (row < 40) code[row][col] = code_of(acc[r]);
      }
    }
  }

  // Gram tiles: wave0 -> (0,0) + (2,2); wave1 -> (1,1); wave2 -> (0,2); wave3 -> (1,2)
  {
    const int q = lane >> 4;
    const int c = lane & 15;
    const int ti = (wave == 1 || wave == 3) ? 1 : 0;
    const int tj = (wave >= 2) ? 2 : ti;
    bf16x8 fa[4], fb[4];
#pragma unroll
    for (int ks = 0; ks < 4; ++ks) {
      fa[ks] = *(const bf16x8*)(&As[ti * 16 + fr][ks * 32 + fk]);
      fb[ks] = *(const bf16x8*)(&As[tj * 16 + fr][ks * 32 + fk]);
    }
    f32x4 g = {0.f, 0.f, 0.f, 0.f};
#pragma unroll
    for (int ks = 0; ks < 4; ++ks)
      g = __builtin_amdgcn_mfma_f32_16x16x32_bf16(fa[ks], fb[ks], g, 0, 0, 0);
    if (ti == tj) {
      if ((c >> 2) == q) rednorm[ti * 16 + c] = g[c & 3];
    } else {
      if (c == ti * 4 + q) {
#pragma unroll
        for (int r = 0; r < 4; ++r) reddot[ti * 16 + q * 4 + r] = g[r];
      }
    }
    if (wave == 0) {  // second tile: (2,2) for k-norms (rows 32..39)
      bf16x8 fc[4];
#pragma unroll
      for (int ks = 0; ks < 4; ++ks)
        fc[ks] = *(const bf16x8*)(&As[32 + fr][ks * 32 + fk]);
      f32x4 g2 = {0.f, 0.f, 0.f, 0.f};
#pragma unroll
      for (int ks = 0; ks < 4; ++ks)
        g2 = __builtin_amdgcn_mfma_f32_16x16x32_bf16(fc[ks], fc[ks], g2, 0, 0, 0);
      if ((c >> 2) == q && c < 8) rednorm[32 + c] = g2[c & 3];
    }
  }
  __syncthreads();

  // final: thread (h, sub) sums |qc-kc| over cols c = sub + 8j (stride-8 walk,
  // conflict-free), 8-thread shuffle reduce.
  const int h   = tid >> 3;
  const int sub = tid & 7;
  const int kr  = 32 + (h >> 2);
  float s = 0.f;
#pragma unroll
  for (int j = 0; j < 16; ++j) {
    const int c = sub + 8 * j;
    s += fabsf(code[h][c] - code[kr][c]);
  }
  s += __shfl_down(s, 4, 8);
  s += __shfl_down(s, 2, 8);
  s += __shfl_down(s, 1, 8);
  if (sub == 0) {
    const float invsq = 0.08838834764831843f;  // 1/sqrt(128)
    out[(size_t)b * NH + h] = reddot[h] * invsq;
    const float hamw = (1.0f - s * (1.0f / 64.0f)) *
                       sqrtf(rednorm[h]) * sqrtf(rednorm[kr]) * invsq;
    out[(size_t)(B_TOK * NH) + (size_t)b * NH + h] = hamw;
  }
}

// ---------------- launch ----------------

extern "C" void kernel_launch(void* const* d_in, const int* in_sizes, int n_in,
                              void* d_out, int out_size, void* d_ws, size_t ws_size,
                              hipStream_t stream) {
  const float* hidden = (const float*)d_in[0];   // [8192][4096]
  const float* proj_w = (const float*)d_in[1];   // [4096][6144]
  const float* proj_b = (const float*)d_in[2];   // [6144]
  const float* hash_w = (const float*)d_in[3];   // [128][128]
  float* out = (float*)d_out;                    // [2*262144]

  char* w = (char*)d_ws;
  __bf16* Abf = (__bf16*)(w);                                     // 67,108,864 B
  __bf16* Wt  = (__bf16*)(w + 67108864);                          // 41,943,040 B
  __bf16* QK  = (__bf16*)(w + 67108864 + 41943040);               // 83,886,080 B
  __bf16* hwT = (__bf16*)(w + 67108864 + 41943040 + 83886080);    // 32,768 B

  prep_kernel<<<NB_HID + NB_WT + NB_HASH, 256, 0, stream>>>(hidden, Abf, proj_w, Wt,
                                                            hash_w, hwT);
  gemm_qk<<<dim3(NOUT / 128, B_TOK / 128), 256, 0, stream>>>(Abf, Wt, proj_b, QK);
  phase2_kernel<<<B_TOK, 256, 0, stream>>>(QK, hwT, out);
}